// Round 1
// baseline (212.604 us; speedup 1.0000x reference)
//
#include <hip/hip_runtime.h>
#include <hip/hip_bf16.h>

// C2QAttention: softmax(sim[B,C,Q], axis=Q) @ enc[B,Q,D] -> out[B,C,D]
// B=32, C=4096, Q=512, D=512. All fp32 in/out; bf16 MFMA internally.

constexpr int Bn = 32;
constexpr int Cn = 4096;
constexpr int Qn = 512;
constexpr int Dn = 512;
constexpr int BM = 64;   // C-rows per block

typedef __attribute__((ext_vector_type(8))) short short8;
typedef __attribute__((ext_vector_type(4))) float floatx4;

__device__ __forceinline__ ushort f2bf(float f) {
  union { float f; unsigned u; } v; v.f = f;
  unsigned r = v.u + 0x7FFFu + ((v.u >> 16) & 1u);   // RNE
  return (ushort)(r >> 16);
}

// enc [B][Q][D] f32  ->  Et [B][D][Q] bf16   (transposed so MFMA B-frags are
// contiguous 16B loads along Q)
__global__ __launch_bounds__(256) void transpose_conv(const float* __restrict__ E,
                                                      ushort* __restrict__ Et) {
  __shared__ float tile[32][33];
  int b = blockIdx.z, q0 = blockIdx.y * 32, d0 = blockIdx.x * 32;
  int x = threadIdx.x & 31, y = threadIdx.x >> 5;  // y: 0..7
  const float* src = E + ((size_t)b * Qn + q0) * Dn + d0;
#pragma unroll
  for (int k = 0; k < 4; ++k)
    tile[y + 8 * k][x] = src[(size_t)(y + 8 * k) * Dn + x];
  __syncthreads();
  ushort* dst = Et + ((size_t)b * Dn + d0) * Qn + q0;
#pragma unroll
  for (int k = 0; k < 4; ++k)
    dst[(size_t)(y + 8 * k) * Qn + x] = f2bf(tile[x][y + 8 * k]);
}

// Fused: per-block = one b, 64 C-rows. 8 waves.
// Phase 1: wave-parallel softmax of 8 rows/wave -> bf16 P in swizzled LDS.
// Phase 2: P[64,512] x E[512,512] via 16x16x32 bf16 MFMA; each wave owns a
//          64x64 output tile (M_rep=4, N_rep=4). B-frags read from L2-resident Et.
__global__ __launch_bounds__(512, 4) void c2q_fused(const float* __restrict__ sim,
                                                    const ushort* __restrict__ Et,
                                                    float* __restrict__ out) {
  __shared__ char Plds[BM * Qn * 2];  // 64 KB bf16, XOR-swizzled rows

  const int tid  = threadIdx.x;
  const int lane = tid & 63;
  const int wid  = tid >> 6;          // 0..7
  const int l16  = lane & 15;
  const int lhi  = lane >> 4;         // 0..3
  const int b    = blockIdx.y;
  const int c0   = blockIdx.x * BM;

  // ---------------- softmax phase ----------------
  const float* simb = sim + ((size_t)b * Cn + c0) * Qn;
  for (int i = 0; i < 8; ++i) {
    int r = wid * 8 + i;
    const float4* src = (const float4*)(simb + (size_t)r * Qn) + lane * 2;
    float4 v0 = src[0], v1 = src[1];
    float mx = fmaxf(fmaxf(fmaxf(v0.x, v0.y), fmaxf(v0.z, v0.w)),
                     fmaxf(fmaxf(v1.x, v1.y), fmaxf(v1.z, v1.w)));
#pragma unroll
    for (int m = 1; m < 64; m <<= 1) mx = fmaxf(mx, __shfl_xor(mx, m));
    float e[8];
    e[0] = __expf(v0.x - mx); e[1] = __expf(v0.y - mx);
    e[2] = __expf(v0.z - mx); e[3] = __expf(v0.w - mx);
    e[4] = __expf(v1.x - mx); e[5] = __expf(v1.y - mx);
    e[6] = __expf(v1.z - mx); e[7] = __expf(v1.w - mx);
    float s = ((e[0] + e[1]) + (e[2] + e[3])) + ((e[4] + e[5]) + (e[6] + e[7]));
#pragma unroll
    for (int m = 1; m < 64; m <<= 1) s += __shfl_xor(s, m);
    float inv = 1.0f / s;
    uint4 pk;
    pk.x = (uint)f2bf(e[0] * inv) | ((uint)f2bf(e[1] * inv) << 16);
    pk.y = (uint)f2bf(e[2] * inv) | ((uint)f2bf(e[3] * inv) << 16);
    pk.z = (uint)f2bf(e[4] * inv) | ((uint)f2bf(e[5] * inv) << 16);
    pk.w = (uint)f2bf(e[6] * inv) | ((uint)f2bf(e[7] * inv) << 16);
    int off = (r << 10) + (lane << 4);
    off ^= (r & 7) << 4;               // bank-conflict swizzle
    *(uint4*)(Plds + off) = pk;
  }
  __syncthreads();

  // ---------------- GEMM phase ----------------
  floatx4 acc[4][4] = {};
  // B-frag base: Et row = d-index = wid*64 + nr*16 + l16 ; k = ks*32 + lhi*8 + j
  const ushort* EtB = Et + ((size_t)b * Dn + wid * 64 + l16) * Qn + lhi * 8;

#pragma unroll 4
  for (int ks = 0; ks < 16; ++ks) {
    short8 a[4], bb[4];
#pragma unroll
    for (int mr = 0; mr < 4; ++mr) {
      int row = mr * 16 + l16;
      int off = (row << 10) + (ks << 6) + (lhi << 4);
      off ^= (row & 7) << 4;
      a[mr] = *(const short8*)(Plds + off);
    }
#pragma unroll
    for (int nr = 0; nr < 4; ++nr)
      bb[nr] = *(const short8*)(EtB + (size_t)nr * 16 * Qn + ks * 32);
#pragma unroll
    for (int mr = 0; mr < 4; ++mr)
#pragma unroll
      for (int nr = 0; nr < 4; ++nr)
        acc[mr][nr] = __builtin_amdgcn_mfma_f32_16x16x32_bf16(a[mr], bb[nr],
                                                              acc[mr][nr], 0, 0, 0);
  }

  // ---------------- epilogue ----------------
  float* outp = out + ((size_t)b * Cn + c0) * Dn;
#pragma unroll
  for (int mr = 0; mr < 4; ++mr)
#pragma unroll
    for (int nr = 0; nr < 4; ++nr)
#pragma unroll
      for (int rr = 0; rr < 4; ++rr) {
        int row = mr * 16 + lhi * 4 + rr;
        int col = wid * 64 + nr * 16 + l16;
        outp[(size_t)row * Dn + col] = acc[mr][nr][rr];
      }
}

extern "C" void kernel_launch(void* const* d_in, const int* in_sizes, int n_in,
                              void* d_out, int out_size, void* d_ws, size_t ws_size,
                              hipStream_t stream) {
  const float* sim = (const float*)d_in[0];
  const float* enc = (const float*)d_in[1];
  float* outp = (float*)d_out;
  ushort* Et = (ushort*)d_ws;  // needs 32*512*512*2 = 16.8 MB

  transpose_conv<<<dim3(Dn / 32, Qn / 32, Bn), 256, 0, stream>>>(enc, Et);
  c2q_fused<<<dim3(Cn / BM, Bn), 512, 0, stream>>>(sim, Et, outp);
}